// Round 12
// baseline (193.990 us; speedup 1.0000x reference)
//
#include <hip/hip_runtime.h>
#include <hip/hip_bf16.h>

#define S_LEN 2048
#define NHEADS 8
#define DHEAD 64
#define NBATCH 4
#define DMODEL 512
#define NJOBS 5120

typedef __attribute__((ext_vector_type(8))) short short8;
typedef __attribute__((ext_vector_type(4))) short short4v;
typedef __attribute__((ext_vector_type(4))) float f32x4;

__device__ __forceinline__ short f2bf(float f) {
    unsigned int u = __builtin_bit_cast(unsigned int, f);
    u = (u + 0x7fffu + ((u >> 16) & 1u)) >> 16;
    return (short)u;
}

// ---------------- Er f32 -> bf16 ----------------
__global__ __launch_bounds__(256) void er_convert(const float* __restrict__ er,
                                                  unsigned short* __restrict__ erb) {
    int i = (blockIdx.x * 256 + threadIdx.x) * 4;
    float4 v = *(const float4*)(er + i);
    short4v s;
    s[0] = f2bf(v.x); s[1] = f2bf(v.y); s[2] = f2bf(v.z); s[3] = f2bf(v.w);
    *(short4v*)(erb + i) = s;
}

// ---------------- QKV projection: y[m,n] = sum_k x[m,k]*W[n,k] + b[n] ----------------
// Q,K bf16 in [mat][b][h][s][dh]; V written TRANSPOSED: [b][h][dh][s].
// Q is PRE-SCALED by 1/(8*ln2).
__global__ __launch_bounds__(256) void qkv_gemm(
    const float* __restrict__ x,
    const float* __restrict__ Wq, const float* __restrict__ bq,
    const float* __restrict__ Wk, const float* __restrict__ bk,
    const float* __restrict__ Wv, const float* __restrict__ bv,
    unsigned short* __restrict__ qkv)
{
    __shared__ __align__(16) short smem[64 * 136];
    short* xt = smem;
    short* wt = smem + 128 * 40;
    const int tid = threadIdx.x;
    const int w = tid >> 6;
    const int l = tid & 63;
    const int lrow = l & 15, lgrp = l >> 4;
    const int m0 = blockIdx.x * 128;
    const int nb = blockIdx.y;
    const int mat = nb >> 3, hh = nb & 7;
    const float* W    = (mat == 0) ? Wq : ((mat == 1) ? Wk : Wv);
    const float* bias = (mat == 0) ? bq : ((mat == 1) ? bk : bv);
    const int n0 = hh * 64;

    f32x4 acc[2][4];
    #pragma unroll
    for (int i = 0; i < 2; i++)
        #pragma unroll
        for (int j = 0; j < 4; j++) acc[i][j] = (f32x4)0.0f;

    const int xrow = tid >> 1, xseg = tid & 1;
    const int wrow = tid >> 2, wseg = tid & 3;

    for (int k0 = 0; k0 < DMODEL; k0 += 32) {
        const float* xs = x + (size_t)(m0 + xrow) * DMODEL + k0 + xseg * 16;
        float4 a0 = *(const float4*)(xs);
        float4 a1 = *(const float4*)(xs + 4);
        float4 a2 = *(const float4*)(xs + 8);
        float4 a3 = *(const float4*)(xs + 12);
        const float* wsrc = W + (size_t)(n0 + wrow) * DMODEL + k0 + wseg * 8;
        float4 b0 = *(const float4*)(wsrc);
        float4 b1 = *(const float4*)(wsrc + 4);
        short8 sa0, sa1, sb;
        sa0[0]=f2bf(a0.x); sa0[1]=f2bf(a0.y); sa0[2]=f2bf(a0.z); sa0[3]=f2bf(a0.w);
        sa0[4]=f2bf(a1.x); sa0[5]=f2bf(a1.y); sa0[6]=f2bf(a1.z); sa0[7]=f2bf(a1.w);
        sa1[0]=f2bf(a2.x); sa1[1]=f2bf(a2.y); sa1[2]=f2bf(a2.z); sa1[3]=f2bf(a2.w);
        sa1[4]=f2bf(a3.x); sa1[5]=f2bf(a3.y); sa1[6]=f2bf(a3.z); sa1[7]=f2bf(a3.w);
        sb[0]=f2bf(b0.x); sb[1]=f2bf(b0.y); sb[2]=f2bf(b0.z); sb[3]=f2bf(b0.w);
        sb[4]=f2bf(b1.x); sb[5]=f2bf(b1.y); sb[6]=f2bf(b1.z); sb[7]=f2bf(b1.w);
        *(short8*)(xt + xrow * 40 + xseg * 16)     = sa0;
        *(short8*)(xt + xrow * 40 + xseg * 16 + 8) = sa1;
        *(short8*)(wt + wrow * 40 + wseg * 8)      = sb;
        __syncthreads();
        #pragma unroll
        for (int nc = 0; nc < 4; nc++) {
            short8 bfrag = *(const short8*)(wt + (nc * 16 + lrow) * 40 + lgrp * 8);
            #pragma unroll
            for (int mf = 0; mf < 2; mf++) {
                short8 afrag = *(const short8*)(xt + (w * 32 + mf * 16 + lrow) * 40 + lgrp * 8);
                acc[mf][nc] = __builtin_amdgcn_mfma_f32_16x16x32_bf16(afrag, bfrag, acc[mf][nc], 0, 0, 0);
            }
        }
        __syncthreads();
    }

    const int b  = m0 >> 11;
    const int s0 = m0 & (S_LEN - 1);
    if (mat == 2) {
        short* vl = smem;   // 64 x 136 shorts
        #pragma unroll
        for (int nc = 0; nc < 4; nc++) {
            const int d = nc * 16 + lrow;
            const float bias_v = bias[n0 + d];
            #pragma unroll
            for (int mf = 0; mf < 2; mf++)
                #pragma unroll
                for (int r = 0; r < 4; r++) {
                    const int sl = w * 32 + mf * 16 + lgrp * 4 + r;
                    vl[d * 136 + sl] = f2bf(acc[mf][nc][r] + bias_v);
                }
        }
        __syncthreads();
        unsigned short* ob = qkv + (((size_t)2 * NBATCH + b) * NHEADS + hh) * S_LEN * DHEAD;
        #pragma unroll
        for (int kch = 0; kch < 4; kch++) {
            const int c = kch * 256 + tid;
            const int d = c >> 4, seg = c & 15;
            short8 ch = *(const short8*)(vl + d * 136 + seg * 8);
            *(short8*)(ob + (size_t)d * S_LEN + s0 + seg * 8) = ch;
        }
    } else {
        const float oscale = (mat == 0) ? 0.18033688f : 1.0f;   // Q: 1/(8*ln2)
        unsigned short* ob = qkv + (((size_t)mat * NBATCH + b) * NHEADS + hh) * S_LEN * DHEAD;
        #pragma unroll
        for (int nc = 0; nc < 4; nc++) {
            const int d = nc * 16 + lrow;
            const float bias_v = bias[n0 + d];
            #pragma unroll
            for (int mf = 0; mf < 2; mf++) {
                #pragma unroll
                for (int r = 0; r < 4; r++) {
                    int srow = s0 + w * 32 + mf * 16 + lgrp * 4 + r;
                    ob[(size_t)srow * DHEAD + d] =
                        (unsigned short)f2bf((acc[mf][nc][r] + bias_v) * oscale);
                }
            }
        }
    }
}

// ---------------- fused causal attention with relative (skew) bias ----------------
// P = exp2(q'.k[t] + q'.Er[t-s+S-1]), t <= s (scale folded into Q).
// Job = (bh, 32-row strip, chunk of <=8 KV-tiles) -> 5120 jobs, heavy-first,
// pulled by 1792 persistent blocks (R11's 2048:1792 ratio degenerated to
// static assignment; tail chain was 32 tiles, now 8). Disjoint-t partials of
// the no-max softmax ADD, so chunks merge via HW f32 atomicAdd into out
// (zeroed) + l_part; rga_norm divides in place.
__global__ __launch_bounds__(128) void rga_attn(
    const unsigned short* __restrict__ qkv,
    const unsigned short* __restrict__ er,
    float* __restrict__ out,
    float* __restrict__ lpart,
    int* __restrict__ counter)
{
    __shared__ __align__(16) unsigned short klds[64 * 64];      // [t][d], rows 128B xor-swizzled
    __shared__ __align__(16) unsigned short vt[64 * 72];        // [d][t], stride 72 (pad)
    __shared__ __align__(16) unsigned short plds[2][16 * 64];   // per-wave P, rows 128B xor-swizzled
    __shared__ int jobsh;

    const int tid = threadIdx.x;
    const int w = tid >> 6;
    const int l = tid & 63;
    const int lrow = l & 15, lgrp = l >> 4;
    const int trb = tid >> 3, seg = tid & 7;   // staging: unit j = row trb + 16j

    short8 ones;
    #pragma unroll
    for (int e = 0; e < 8; e++) ones[e] = (short)0x3F80;   // bf16 1.0

    for (;;) {
        if (tid == 0) jobsh = atomicAdd(counter, 1);
        __syncthreads();
        const int job = jobsh;
        __syncthreads();          // jobsh consumed before next job overwrites
        if (job >= NJOBS) return;

        // heavy-first decode: pair -> (sid, chunk); 4/3/2/1 chunks per sid group
        const int pair = job >> 5;
        const int bh   = job & 31;
        int sid, chunk;
        if (pair < 64)        { sid = 63 - (pair >> 2); chunk = pair & 3; }
        else if (pair < 112)  { int p = pair - 64; int d3 = p / 3; sid = 47 - d3; chunk = p - 3 * d3; }
        else if (pair < 144)  { int p = pair - 112; sid = 31 - (p >> 1); chunk = p & 1; }
        else                  { sid = 15 - (pair - 144); chunk = 0; }

        const int b = bh >> 3, hh = bh & 7;
        const int q0 = sid * 32;
        const int s_base = q0 + w * 16;
        const int nt = (sid >> 1) + 1;
        const int it0 = chunk << 3;
        const int it1 = (it0 + 8 < nt) ? (it0 + 8) : nt;

        const unsigned short* qp  = qkv + (size_t)bh * S_LEN * DHEAD;
        const unsigned short* kp  = qkv + ((size_t)(NBATCH * NHEADS) + bh) * S_LEN * DHEAD;
        const unsigned short* vtg = qkv + ((size_t)(2 * NBATCH * NHEADS) + bh) * S_LEN * DHEAD;

        short8 aq[2];
        {
            const unsigned short* qr = qp + (size_t)(s_base + lrow) * DHEAD + lgrp * 8;
            aq[0] = *(const short8*)(qr);
            aq[1] = *(const short8*)(qr + 32);
        }

        f32x4 o[4], lsum;
        lsum = (f32x4)0.0f;
        #pragma unroll
        for (int n = 0; n < 4; n++) o[n] = (f32x4)0.0f;

        // prologue: prefetch tile it0 (K/V staged cooperatively, Er per wave)
        short8 kreg[4], vreg[4];
        #pragma unroll
        for (int j = 0; j < 4; j++) {
            kreg[j] = *(const short8*)(kp + (size_t)(it0 * 64 + trb + 16 * j) * DHEAD + seg * 8);
            vreg[j] = *(const short8*)(vtg + (size_t)(trb + 16 * j) * S_LEN + it0 * 64 + seg * 8);
        }
        short8 ereg0[5], ereg1[5];
        {
            const int r_lo = it0 * 64 - s_base + (S_LEN - 16);
            #pragma unroll
            for (int f = 0; f < 5; f++) {
                int rr = r_lo + f * 16 + lrow;
                rr = rr < 0 ? 0 : (rr > (S_LEN - 1) ? (S_LEN - 1) : rr);
                const unsigned short* ep = er + (size_t)rr * DHEAD + lgrp * 8;
                ereg0[f] = *(const short8*)(ep);
                ereg1[f] = *(const short8*)(ep + 32);
            }
        }

        unsigned short* pw = plds[w];

        for (int it = it0; it < it1; it++) {
            const int t0 = it << 6;
            __syncthreads();   // previous tile's compute done; LDS free
            #pragma unroll
            for (int j = 0; j < 4; j++) {
                const int tr = trb + 16 * j;
                *(short8*)((char*)klds + tr * 128 + ((seg * 16) ^ ((tr & 7) << 4))) = kreg[j];
                *(short8*)(vt + tr * 72 + seg * 8) = vreg[j];
            }
            __syncthreads();   // LDS tile ready

            // ---- QEr band (prefetched regs): 5 frags cover jr in [0,79] ----
            f32x4 qe[5];
            __builtin_amdgcn_s_setprio(1);
            #pragma unroll
            for (int f = 0; f < 5; f++) {
                f32x4 a = (f32x4)0.0f;
                a = __builtin_amdgcn_mfma_f32_16x16x32_bf16(aq[0], ereg0[f], a, 0, 0, 0);
                a = __builtin_amdgcn_mfma_f32_16x16x32_bf16(aq[1], ereg1[f], a, 0, 0, 0);
                qe[f] = a;
            }
            __builtin_amdgcn_s_setprio(0);

            if (it + 1 < it1) {   // issue next tile's K/V and Er loads
                #pragma unroll
                for (int j = 0; j < 4; j++) {
                    const int tr = trb + 16 * j;
                    kreg[j] = *(const short8*)(kp + (size_t)(t0 + 64 + tr) * DHEAD + seg * 8);
                    vreg[j] = *(const short8*)(vtg + (size_t)tr * S_LEN + t0 + 64 + seg * 8);
                }
                const int r_lo = t0 + 64 - s_base + (S_LEN - 16);
                #pragma unroll
                for (int f = 0; f < 5; f++) {
                    int rr = r_lo + f * 16 + lrow;
                    rr = rr < 0 ? 0 : (rr > (S_LEN - 1) ? (S_LEN - 1) : rr);
                    const unsigned short* ep = er + (size_t)rr * DHEAD + lgrp * 8;
                    ereg0[f] = *(const short8*)(ep);
                    ereg1[f] = *(const short8*)(ep + 32);
                }
            }

            // ---- QK^T: 16 rows x 64 t ----
            f32x4 sfr[4];
            __builtin_amdgcn_s_setprio(1);
            #pragma unroll
            for (int u = 0; u < 4; u++) {
                const int trow = u * 16 + lrow;
                const char* kb = (const char*)klds + trow * 128;
                const int swz = (trow & 7) << 4;
                short8 kb0 = *(const short8*)(kb + ((lgrp * 16) ^ swz));
                short8 kb1 = *(const short8*)(kb + ((64 + lgrp * 16) ^ swz));
                f32x4 a = (f32x4)0.0f;
                a = __builtin_amdgcn_mfma_f32_16x16x32_bf16(aq[0], kb0, a, 0, 0, 0);
                a = __builtin_amdgcn_mfma_f32_16x16x32_bf16(aq[1], kb1, a, 0, 0, 0);
                sfr[u] = a;
            }
            __builtin_amdgcn_s_setprio(0);

            // ---- band gather + mask + exp2 (v_exp_f32) + cvt_pk pack -> LDS ----
            #pragma unroll
            for (int r = 0; r < 4; r++) {
                const int si = lgrp * 4 + r;
                const int sg = s_base + si;
                const int dd = lrow - si + 15;            // [0,30]
                const int srcl = (l & 48) | (dd & 15);
                const int hi = dd >> 4;
                float sh[5];
                #pragma unroll
                for (int f = 0; f < 5; f++) sh[f] = __shfl(qe[f][r], srcl);
                const int pswz = (si & 7) << 4;
                char* pr = (char*)pw + si * 128;
                float pe[4];
                #pragma unroll
                for (int u = 0; u < 4; u++) {
                    const float rel = hi ? sh[u + 1] : sh[u];
                    float sc = sfr[u][r] + rel;            // scale folded into Q
                    float ex;
                    asm("v_exp_f32 %0, %1\ns_nop 1" : "=v"(ex) : "v"(sc));
                    pe[u] = ((t0 + u * 16 + lrow) <= sg) ? ex : 0.0f;
                }
                #pragma unroll
                for (int h2 = 0; h2 < 2; h2++) {
                    unsigned pk;
                    asm("v_cvt_pk_bf16_f32 %0, %1, %2"
                        : "=v"(pk) : "v"(pe[h2 * 2]), "v"(pe[h2 * 2 + 1]));
                    *(unsigned short*)(pr + (((h2 * 32 + lrow) * 2) ^ pswz)) = (unsigned short)pk;
                    *(unsigned short*)(pr + (((h2 * 32 + 16 + lrow) * 2) ^ pswz)) = (unsigned short)(pk >> 16);
                }
            }
            asm volatile("s_waitcnt lgkmcnt(0)" ::: "memory");
            __builtin_amdgcn_sched_barrier(0);
            // ---- PV + row-sum (denominator) ----
            __builtin_amdgcn_s_setprio(1);
            const int pswz2 = (lrow & 7) << 4;
            #pragma unroll
            for (int kk = 0; kk < 2; kk++) {
                short8 pa = *(const short8*)((const char*)pw + lrow * 128 +
                                             ((kk * 64 + lgrp * 16) ^ pswz2));
                lsum = __builtin_amdgcn_mfma_f32_16x16x32_bf16(pa, ones, lsum, 0, 0, 0);
                #pragma unroll
                for (int n = 0; n < 4; n++) {
                    short8 vb = *(const short8*)(vt + (n * 16 + lrow) * 72 + kk * 32 + lgrp * 8);
                    o[n] = __builtin_amdgcn_mfma_f32_16x16x32_bf16(pa, vb, o[n], 0, 0, 0);
                }
            }
            __builtin_amdgcn_s_setprio(0);
        }

        // ---- merge chunk partials: HW f32 atomics into out + lpart ----
        #pragma unroll
        for (int r = 0; r < 4; r++) {
            const int sg = s_base + lgrp * 4 + r;
            float* orow = out + ((size_t)b * S_LEN + sg) * DMODEL + hh * DHEAD;
            #pragma unroll
            for (int n = 0; n < 4; n++)
                unsafeAtomicAdd(&orow[n * 16 + lrow], o[n][r]);
            if (lrow == 0)
                unsafeAtomicAdd(&lpart[bh * S_LEN + sg], lsum[r]);
        }
        __syncthreads();   // all waves done with LDS before next job's staging
    }
}

// ---------------- normalize: out /= lpart ----------------
__global__ __launch_bounds__(256) void rga_norm(float* __restrict__ out,
                                                const float* __restrict__ lpart) {
    const int v = blockIdx.x * 256 + threadIdx.x;   // float4 index
    const int flat = v << 2;
    const int s  = (flat >> 9) & (S_LEN - 1);
    const int b  = flat >> 20;
    const int h  = (flat & 511) >> 6;
    const float inv = 1.0f / lpart[(b * NHEADS + h) * S_LEN + s];
    float4 t = *(float4*)(out + flat);
    t.x *= inv; t.y *= inv; t.z *= inv; t.w *= inv;
    *(float4*)(out + flat) = t;
}

extern "C" void kernel_launch(void* const* d_in, const int* in_sizes, int n_in,
                              void* d_out, int out_size, void* d_ws, size_t ws_size,
                              hipStream_t stream) {
    const float* x  = (const float*)d_in[0];
    const float* Wq = (const float*)d_in[1];
    const float* bq = (const float*)d_in[2];
    const float* Wk = (const float*)d_in[3];
    const float* bk = (const float*)d_in[4];
    const float* Wv = (const float*)d_in[5];
    const float* bv = (const float*)d_in[6];
    const float* Er = (const float*)d_in[7];

    unsigned short* ws_qkv = (unsigned short*)d_ws;                       // Q,K [b][h][s][d]; V^T [b][h][d][s]
    unsigned short* ws_er  = ws_qkv + (size_t)3 * NBATCH * NHEADS * S_LEN * DHEAD;
    float* ws_lpart = (float*)(ws_er + (size_t)S_LEN * DHEAD);
    int* ws_counter = (int*)(ws_lpart + (size_t)NBATCH * NHEADS * S_LEN);

    hipMemsetAsync(d_out, 0, (size_t)out_size * sizeof(float), stream);
    hipMemsetAsync(ws_lpart, 0, (size_t)NBATCH * NHEADS * S_LEN * sizeof(float) + sizeof(int), stream);
    er_convert<<<dim3(128), dim3(256), 0, stream>>>(Er, ws_er);
    qkv_gemm<<<dim3(64, 24), dim3(256), 0, stream>>>(x, Wq, bq, Wk, bk, Wv, bv, ws_qkv);
    rga_attn<<<dim3(1792), dim3(128), 0, stream>>>(ws_qkv, ws_er, (float*)d_out, ws_lpart, ws_counter);
    rga_norm<<<dim3((NBATCH * S_LEN * DMODEL) / 1024), dim3(256), 0, stream>>>((float*)d_out, ws_lpart);
}